// Round 5
// baseline (369.697 us; speedup 1.0000x reference)
//
#include <hip/hip_runtime.h>
#include <stdint.h>

typedef __attribute__((ext_vector_type(8))) short short8;
typedef __attribute__((ext_vector_type(4))) float f32x4;

__device__ __forceinline__ unsigned short f2bf(float f) {
  unsigned u = __float_as_uint(f);
  u += 0x7FFF + ((u >> 16) & 1);
  return (unsigned short)(u >> 16);
}
__device__ __forceinline__ float bf2f(unsigned short h) {
  return __uint_as_float(((unsigned)h) << 16);
}

// ---------------- f32 -> bf16 convert (x4 vectorized) ----------------
__global__ __launch_bounds__(256) void k_cvt(const float* __restrict__ in,
                                             unsigned short* __restrict__ out, int n4) {
  int i = blockIdx.x * 256 + threadIdx.x;
  if (i >= n4) return;
  float4 v = ((const float4*)in)[i];
  ushort4 o;
  o.x = f2bf(v.x); o.y = f2bf(v.y); o.z = f2bf(v.z); o.w = f2bf(v.w);
  ((ushort4*)out)[i] = o;
}

// ---------------- zero the seq-pad columns of Vt ----------------
__global__ __launch_bounds__(256) void k_zpad(unsigned short* __restrict__ vt) {
  const int TOT = 768 * 64 * 27;
  int i = blockIdx.x * 256 + threadIdx.x;
  if (i >= TOT) return;
  int row = i / 27, c = i - row * 27;
  vt[row * 224 + 197 + c] = 0;
}

// ---------------- fused: x f32 -> bf16 + low = 2*X@A^T ----------------
__global__ __launch_bounds__(256) void k_lowcvt(const float* __restrict__ x,
                                                const float* __restrict__ lora_a,
                                                unsigned short* __restrict__ xbf,
                                                float* __restrict__ low, int M) {
  __shared__ float As[8 * 768];
  for (int i = threadIdx.x; i < 8 * 768; i += 256) As[i] = lora_a[i];
  __syncthreads();
  int w = threadIdx.x >> 6, l = threadIdx.x & 63;
  int m = blockIdx.x * 4 + w;
  if (m >= M) return;
  float acc[8] = {0, 0, 0, 0, 0, 0, 0, 0};
  for (int j = 0; j < 12; ++j) {
    int d = j * 64 + l;
    float xv = x[(size_t)m * 768 + d];
    xbf[(size_t)m * 768 + d] = f2bf(xv);
#pragma unroll
    for (int r = 0; r < 8; ++r) acc[r] += xv * As[r * 768 + d];
  }
#pragma unroll
  for (int r = 0; r < 8; ++r)
    for (int dd = 1; dd < 64; dd <<= 1) acc[r] += __shfl_xor(acc[r], dd);
  if (l == 0) {
#pragma unroll
    for (int r = 0; r < 8; ++r) low[m * 8 + r] = 2.0f * acc[r];
  }
}

// ---------------- rank-8 LoRA low = 2 * X @ A^T  (bf16 input) ----------------
__global__ __launch_bounds__(256) void k_low(const unsigned short* __restrict__ xin,
                                             const float* __restrict__ lora_a,
                                             float* __restrict__ low, int M) {
  __shared__ float As[8 * 768];
  for (int i = threadIdx.x; i < 8 * 768; i += 256) As[i] = lora_a[i];
  __syncthreads();
  int w = threadIdx.x >> 6, l = threadIdx.x & 63;
  int m = blockIdx.x * 4 + w;
  if (m >= M) return;
  float acc[8] = {0, 0, 0, 0, 0, 0, 0, 0};
  for (int j = 0; j < 12; ++j) {
    int d = j * 64 + l;
    float xv = bf2f(xin[(size_t)m * 768 + d]);
#pragma unroll
    for (int r = 0; r < 8; ++r) acc[r] += xv * As[r * 768 + d];
  }
#pragma unroll
  for (int r = 0; r < 8; ++r)
    for (int dd = 1; dd < 64; dd <<= 1) acc[r] += __shfl_xor(acc[r], dd);
  if (l == 0) {
#pragma unroll
    for (int r = 0; r < 8; ++r) low[m * 8 + r] = 2.0f * acc[r];
  }
}

// ---------------- direct-from-global GEMM: 1 wave = 64x64 tile, no LDS, no barriers ----------------
// C[M,N] = A[M,768] x B[N,768]^T, M = 197*64 exactly (no tail).
// MODE 0: N=2304 (NT=36), epilogue scatters to Q/K/Vt (bf16), per-wave strip = one (which,head).
// MODE 1: N=768 (NT=12), epilogue writes f32 out.
template <int MODE, int NT>
__global__ __launch_bounds__(256, 3) void k_gemm_d(
    const unsigned short* __restrict__ A, const unsigned short* __restrict__ Bw,
    const float* __restrict__ bias, const float* __restrict__ low,
    const float* __restrict__ lorab, unsigned short* __restrict__ Qg,
    unsigned short* __restrict__ Kg, unsigned short* __restrict__ Vtg,
    float* __restrict__ outp) {
  const int w = threadIdx.x >> 6, l = threadIdx.x & 63;
  const int lr = l & 15, lg = l >> 4;
  // bijective XCD swizzle (m204) on blocks; 4 waves/block take consecutive tiles
  const int nwg = gridDim.x;
  const int orig = blockIdx.x;
  const int qq = nwg >> 3, rr = nwg & 7, xcd = orig & 7;
  const int wgid = (xcd < rr ? xcd * (qq + 1) : rr * (qq + 1) + (xcd - rr) * qq) + (orig >> 3);
  const int gt = wgid * 4 + w;           // global wave-tile id
  const int mt = gt / NT, nt = gt - mt * NT;
  const int m0 = mt * 64, n0 = nt * 64;

  // per-lane fragment base pointers (8 total); K-step offsets are immediates
  const unsigned short* pA0 = A + (size_t)(m0 + lr) * 768 + lg * 8;
  const unsigned short* pB0 = Bw + (size_t)(n0 + lr) * 768 + lg * 8;

  f32x4 acc[4][4];
#pragma unroll
  for (int i = 0; i < 4; ++i)
#pragma unroll
    for (int j = 0; j < 4; ++j) acc[i][j] = (f32x4){0.f, 0.f, 0.f, 0.f};

#pragma unroll
  for (int kt = 0; kt < 24; ++kt) {
    short8 af[4], bfr[4];
#pragma unroll
    for (int mf = 0; mf < 4; ++mf) af[mf] = *(const short8*)(pA0 + mf * (16 * 768) + kt * 32);
#pragma unroll
    for (int nf = 0; nf < 4; ++nf) bfr[nf] = *(const short8*)(pB0 + nf * (16 * 768) + kt * 32);
#pragma unroll
    for (int mf = 0; mf < 4; ++mf)
#pragma unroll
      for (int nf = 0; nf < 4; ++nf)
        acc[mf][nf] = __builtin_amdgcn_mfma_f32_16x16x32_bf16(af[mf], bfr[nf], acc[mf][nf], 0, 0, 0);
  }

  // epilogue: bias + rank-8 LoRA
  float bo[4];
  float4 lb0[4], lb1[4];
#pragma unroll
  for (int nf = 0; nf < 4; ++nf) {
    int o = n0 + nf * 16 + lr;
    bo[nf] = bias[o];
    const float4* lb4 = (const float4*)(lorab + (size_t)o * 8);
    lb0[nf] = lb4[0];
    lb1[nf] = lb4[1];
  }
  // MODE 0: this wave's 64-col strip is exactly one (which, head)
  const int which = nt / 12;
  const int hh = nt - which * 12;
#pragma unroll
  for (int mf = 0; mf < 4; ++mf) {
#pragma unroll
    for (int v = 0; v < 4; ++v) {
      int m = m0 + mf * 16 + lg * 4 + v;
      const float4* lp4 = (const float4*)(low + (size_t)m * 8);
      float4 l0 = lp4[0], l1 = lp4[1];
      int b = m / 197;
      int n = m - b * 197;
#pragma unroll
      for (int nf = 0; nf < 4; ++nf) {
        float val = acc[mf][nf][v] + bo[nf];
        val += l0.x * lb0[nf].x + l0.y * lb0[nf].y + l0.z * lb0[nf].z + l0.w * lb0[nf].w;
        val += l1.x * lb1[nf].x + l1.y * lb1[nf].y + l1.z * lb1[nf].z + l1.w * lb1[nf].w;
        if (MODE == 0) {
          int hd = nf * 16 + lr;
          int bh = b * 12 + hh;
          unsigned short hv = f2bf(val);
          if (which == 0)      Qg[(bh * 224 + n) * 64 + hd] = hv;
          else if (which == 1) Kg[(bh * 224 + n) * 64 + hd] = hv;
          else                 Vtg[(bh * 64 + hd) * 224 + n] = hv;
        } else {
          outp[(size_t)m * 768 + n0 + nf * 16 + lr] = val;
        }
      }
    }
  }
}

// ---------------- attention: one block per (b,h), full-row softmax ----------------
__global__ __launch_bounds__(256) void k_attn(const unsigned short* __restrict__ Qg,
                                              const unsigned short* __restrict__ Kg,
                                              const unsigned short* __restrict__ Vtg,
                                              unsigned short* __restrict__ aout) {
  __shared__ __align__(16) unsigned short Ps[4][16 * 224];
  const int bh = blockIdx.x;
  const int b = bh / 12, h = bh - b * 12;
  const unsigned short* Qb = Qg + (size_t)bh * (224 * 64);
  const unsigned short* Kb = Kg + (size_t)bh * (224 * 64);
  const unsigned short* Vb = Vtg + (size_t)bh * (64 * 224);
  const int w = threadIdx.x >> 6, l = threadIdx.x & 63;
  const int lr = l & 15, lg = l >> 4;
  for (int t = w; t < 13; t += 4) {
    const int q0 = t * 16;
    short8 aq0 = *(const short8*)(Qb + (q0 + lr) * 64 + lg * 8);
    short8 aq1 = *(const short8*)(Qb + (q0 + lr) * 64 + 32 + lg * 8);
    f32x4 s[14];
#pragma unroll
    for (int jt = 0; jt < 14; ++jt) {
      f32x4 a = (f32x4){0.f, 0.f, 0.f, 0.f};
      short8 bk0 = *(const short8*)(Kb + (jt * 16 + lr) * 64 + lg * 8);
      short8 bk1 = *(const short8*)(Kb + (jt * 16 + lr) * 64 + 32 + lg * 8);
      a = __builtin_amdgcn_mfma_f32_16x16x32_bf16(aq0, bk0, a, 0, 0, 0);
      a = __builtin_amdgcn_mfma_f32_16x16x32_bf16(aq1, bk1, a, 0, 0, 0);
      s[jt] = a;
    }
    float mx[4] = {-3.0e38f, -3.0e38f, -3.0e38f, -3.0e38f};
#pragma unroll
    for (int jt = 0; jt < 14; ++jt) {
      bool valid = (jt * 16 + lr) < 197;
#pragma unroll
      for (int v = 0; v < 4; ++v) {
        float sv = valid ? s[jt][v] : -1.0e30f;
        s[jt][v] = sv;
        mx[v] = fmaxf(mx[v], sv);
      }
    }
#pragma unroll
    for (int v = 0; v < 4; ++v) {
      mx[v] = fmaxf(mx[v], __shfl_xor(mx[v], 1));
      mx[v] = fmaxf(mx[v], __shfl_xor(mx[v], 2));
      mx[v] = fmaxf(mx[v], __shfl_xor(mx[v], 4));
      mx[v] = fmaxf(mx[v], __shfl_xor(mx[v], 8));
    }
    float sum[4] = {0.f, 0.f, 0.f, 0.f};
    const float cc = 0.125f * 1.44269504088896341f;
#pragma unroll
    for (int jt = 0; jt < 14; ++jt)
#pragma unroll
      for (int v = 0; v < 4; ++v) {
        float pv = exp2f((s[jt][v] - mx[v]) * cc);
        s[jt][v] = pv;
        sum[v] += pv;
      }
#pragma unroll
    for (int v = 0; v < 4; ++v) {
      sum[v] += __shfl_xor(sum[v], 1);
      sum[v] += __shfl_xor(sum[v], 2);
      sum[v] += __shfl_xor(sum[v], 4);
      sum[v] += __shfl_xor(sum[v], 8);
    }
    float inv[4];
#pragma unroll
    for (int v = 0; v < 4; ++v) inv[v] = 1.0f / sum[v];
    unsigned short* pw = &Ps[w][0];
#pragma unroll
    for (int jt = 0; jt < 14; ++jt)
#pragma unroll
      for (int v = 0; v < 4; ++v)
        pw[(lg * 4 + v) * 224 + jt * 16 + lr] = f2bf(s[jt][v] * inv[v]);
    f32x4 oacc[4];
#pragma unroll
    for (int jo = 0; jo < 4; ++jo) oacc[jo] = (f32x4){0.f, 0.f, 0.f, 0.f};
#pragma unroll
    for (int kk = 0; kk < 7; ++kk) {
      short8 pa = *(const short8*)(pw + lr * 224 + kk * 32 + lg * 8);
#pragma unroll
      for (int jo = 0; jo < 4; ++jo) {
        short8 bv = *(const short8*)(Vb + (jo * 16 + lr) * 224 + kk * 32 + lg * 8);
        oacc[jo] = __builtin_amdgcn_mfma_f32_16x16x32_bf16(pa, bv, oacc[jo], 0, 0, 0);
      }
    }
#pragma unroll
    for (int jo = 0; jo < 4; ++jo)
#pragma unroll
      for (int v = 0; v < 4; ++v) {
        int n = q0 + lg * 4 + v;
        if (n < 197) aout[((size_t)(b * 197 + n)) * 768 + h * 64 + jo * 16 + lr] = f2bf(oacc[jo][v]);
      }
  }
}

extern "C" void kernel_launch(void* const* d_in, const int* in_sizes, int n_in,
                              void* d_out, int out_size, void* d_ws, size_t ws_size,
                              hipStream_t stream) {
  const float* x      = (const float*)d_in[0];
  const float* qkv_w  = (const float*)d_in[1];
  const float* qkv_b  = (const float*)d_in[2];
  const float* qkv_la = (const float*)d_in[3];
  const float* qkv_lb = (const float*)d_in[4];
  const float* out_w  = (const float*)d_in[5];
  const float* out_b  = (const float*)d_in[6];
  const float* out_la = (const float*)d_in[7];
  const float* out_lb = (const float*)d_in[8];
  float* out = (float*)d_out;

  const int M = 64 * 197;  // 12608
  char* p = (char*)d_ws;
  auto carve = [&](size_t bytes) {
    char* r = p;
    p += (bytes + 255) & ~(size_t)255;
    return r;
  };
  unsigned short* xbf  = (unsigned short*)carve((size_t)M * 768 * 2);
  unsigned short* qwbf = (unsigned short*)carve((size_t)2304 * 768 * 2);
  unsigned short* owbf = (unsigned short*)carve((size_t)768 * 768 * 2);
  float* lowq          = (float*)carve((size_t)M * 8 * 4);
  float* lowo          = (float*)carve((size_t)M * 8 * 4);
  unsigned short* Qg   = (unsigned short*)carve((size_t)768 * 224 * 64 * 2);
  unsigned short* Kg   = (unsigned short*)carve((size_t)768 * 224 * 64 * 2);
  unsigned short* Vtg  = (unsigned short*)carve((size_t)768 * 64 * 224 * 2);
  unsigned short* aout = xbf;  // reuse: x_bf16 dead after qkv GEMM

  int n4q = 2304 * 768 / 4, n4o = 768 * 768 / 4;
  k_cvt<<<(n4q + 255) / 256, 256, 0, stream>>>(qkv_w, qwbf, n4q);
  k_cvt<<<(n4o + 255) / 256, 256, 0, stream>>>(out_w, owbf, n4o);
  k_zpad<<<(768 * 64 * 27 + 255) / 256, 256, 0, stream>>>(Vtg);
  k_lowcvt<<<(M + 3) / 4, 256, 0, stream>>>(x, qkv_la, xbf, lowq, M);
  // qkv: 197*36 = 7092 wave-tiles / 4 = 1773 blocks
  k_gemm_d<0, 36><<<1773, 256, 0, stream>>>(xbf, qwbf, qkv_b, lowq, qkv_lb, Qg, Kg, Vtg, nullptr);
  k_attn<<<768, 256, 0, stream>>>(Qg, Kg, Vtg, aout);
  k_low<<<(M + 3) / 4, 256, 0, stream>>>(aout, out_la, lowo, M);
  // out: 197*12 = 2364 wave-tiles / 4 = 591 blocks
  k_gemm_d<1, 12><<<591, 256, 0, stream>>>(aout, owbf, out_b, lowo, out_lb, nullptr, nullptr, nullptr, out);
}

// Round 6
// 272.564 us; speedup vs baseline: 1.3564x; 1.3564x over previous
//
#include <hip/hip_runtime.h>
#include <stdint.h>

typedef __attribute__((ext_vector_type(8))) short short8;
typedef __attribute__((ext_vector_type(4))) float f32x4;

__device__ __forceinline__ unsigned short f2bf(float f) {
  unsigned u = __float_as_uint(f);
  u += 0x7FFF + ((u >> 16) & 1);
  return (unsigned short)(u >> 16);
}
__device__ __forceinline__ float bf2f(unsigned short h) {
  return __uint_as_float(((unsigned)h) << 16);
}

// Packed fragment layout for mfma_f32_16x16x32_bf16 operands:
// tile (rt, kc) covers rows [rt*16, rt*16+16) x k [kc*32, kc*32+32).
// lane L = (row&15) + 16*((k&31)>>3), elem e = k&7.
// addr = ((rt*24 + kc)*64 + L)*8 + e   (K=768 -> kc in [0,24))
// A fragment load in GEMM = per-lane 16B, wave-contiguous 1KB.

// ---------------- pack weights: f32 [N][768] -> packed bf16 ----------------
__global__ __launch_bounds__(256) void k_pack_w(const float* __restrict__ W,
                                                unsigned short* __restrict__ out,
                                                int ntiles) {
  int wv = (blockIdx.x * 256 + threadIdx.x) >> 6;
  int l = threadIdx.x & 63;
  if (wv >= ntiles) return;
  int nt = wv / 24, kc = wv - nt * 24;
  int lr = l & 15, lg = l >> 4;
  const float* src = W + (size_t)(nt * 16 + lr) * 768 + kc * 32 + lg * 8;
  float4 a = *(const float4*)src;
  float4 b = *(const float4*)(src + 4);
  short8 o;
  o[0] = f2bf(a.x); o[1] = f2bf(a.y); o[2] = f2bf(a.z); o[3] = f2bf(a.w);
  o[4] = f2bf(b.x); o[5] = f2bf(b.y); o[6] = f2bf(b.z); o[7] = f2bf(b.w);
  *(short8*)(out + (size_t)wv * 512 + l * 8) = o;
}

// ---------------- zero the seq-pad columns of Vt ----------------
__global__ __launch_bounds__(256) void k_zpad(unsigned short* __restrict__ vt) {
  const int TOT = 768 * 64 * 27;
  int i = blockIdx.x * 256 + threadIdx.x;
  if (i >= TOT) return;
  int row = i / 27, c = i - row * 27;
  vt[row * 224 + 197 + c] = 0;
}

// ---------------- fused: pack x (f32 -> packed bf16) + low = 2*X@A^T ----------------
// one block = one 16-row m-tile (M = 788*16 exactly)
__global__ __launch_bounds__(256) void k_pxl(const float* __restrict__ x,
                                             const float* __restrict__ lora_a,
                                             unsigned short* __restrict__ Apk,
                                             float* __restrict__ low) {
  __shared__ unsigned short xs[16 * 776];
  __shared__ float As[8 * 768];
  const int t = threadIdx.x;
  const int mt = blockIdx.x;
  const float4* x4 = (const float4*)(x + (size_t)mt * 16 * 768);
#pragma unroll
  for (int i = 0; i < 12; ++i) {
    float4 v = x4[i * 256 + t];
    int e0 = (i * 256 + t) * 4;
    int row = e0 / 768, col = e0 - row * 768;
    unsigned short* d = &xs[row * 776 + col];
    d[0] = f2bf(v.x); d[1] = f2bf(v.y); d[2] = f2bf(v.z); d[3] = f2bf(v.w);
  }
  for (int i = t; i < 1536; i += 256) ((float4*)As)[i] = ((const float4*)lora_a)[i];
  __syncthreads();
  const int w = t >> 6, l = t & 63;
  // low for rows w*4 .. w*4+3
  float acc[4][8];
#pragma unroll
  for (int r = 0; r < 4; ++r)
#pragma unroll
    for (int k = 0; k < 8; ++k) acc[r][k] = 0.f;
  for (int j = 0; j < 12; ++j) {
    int d = j * 64 + l;
#pragma unroll
    for (int r = 0; r < 4; ++r) {
      float xv = bf2f(xs[(w * 4 + r) * 776 + d]);
#pragma unroll
      for (int k = 0; k < 8; ++k) acc[r][k] += xv * As[k * 768 + d];
    }
  }
#pragma unroll
  for (int r = 0; r < 4; ++r)
#pragma unroll
    for (int k = 0; k < 8; ++k) {
      float a = acc[r][k];
      for (int dd = 1; dd < 64; dd <<= 1) a += __shfl_xor(a, dd);
      if (l == 0) low[((size_t)mt * 16 + w * 4 + r) * 8 + k] = 2.0f * a;
    }
  // pack: wave w -> kc tiles w*6 .. w*6+5
  const int lr = l & 15, lg = l >> 4;
#pragma unroll
  for (int kk = 0; kk < 6; ++kk) {
    int kc = w * 6 + kk;
    short8 v = *(const short8*)(&xs[lr * 776 + kc * 32 + lg * 8]);
    *(short8*)(Apk + ((size_t)mt * 24 + kc) * 512 + l * 8) = v;
  }
}

// ---------------- rank-8 LoRA low from PACKED bf16 input ----------------
__global__ __launch_bounds__(256) void k_low_pk(const unsigned short* __restrict__ Apk,
                                                const float* __restrict__ lora_a,
                                                float* __restrict__ low, int M) {
  __shared__ float As[8 * 768];
  for (int i = threadIdx.x; i < 1536; i += 256) ((float4*)As)[i] = ((const float4*)lora_a)[i];
  __syncthreads();
  int w = threadIdx.x >> 6, l = threadIdx.x & 63;
  int m = blockIdx.x * 4 + w;
  if (m >= M) return;
  const int mt = m >> 4, mr = m & 15;
  const int kcb = l >> 5, lgp = (l & 31) >> 3, e = l & 7;
  float acc[8] = {0, 0, 0, 0, 0, 0, 0, 0};
  for (int j = 0; j < 12; ++j) {
    int d = j * 64 + l;
    float xv = bf2f(Apk[((size_t)(mt * 24 + j * 2 + kcb) * 64 + mr + 16 * lgp) * 8 + e]);
#pragma unroll
    for (int r = 0; r < 8; ++r) acc[r] += xv * As[r * 768 + d];
  }
#pragma unroll
  for (int r = 0; r < 8; ++r) {
    for (int dd = 1; dd < 64; dd <<= 1) acc[r] += __shfl_xor(acc[r], dd);
    if (l == 0) low[(size_t)m * 8 + r] = 2.0f * acc[r];
  }
}

// ---------------- GEMM from packed fragments: 1 wave = 64x64, no LDS, no barriers ----------------
// MODE 0: qkv (NT=36 n-strips), scatter to Q/K/Vt. MODE 1: out (NT=12), f32 out.
template <int MODE, int NT>
__global__ __launch_bounds__(256, 3) void k_gd_qkv_or_out(
    const unsigned short* __restrict__ Apk, const unsigned short* __restrict__ Bpk,
    const float* __restrict__ bias, const float* __restrict__ low,
    const float* __restrict__ lorab, unsigned short* __restrict__ Qg,
    unsigned short* __restrict__ Kg, unsigned short* __restrict__ Vtg,
    float* __restrict__ outp) {
  const int w = threadIdx.x >> 6, l = threadIdx.x & 63;
  const int lr = l & 15, lg = l >> 4;
  const int nwg = gridDim.x;
  const int orig = blockIdx.x;
  const int qq = nwg >> 3, rr = nwg & 7, xcd = orig & 7;
  const int wgid = (xcd < rr ? xcd * (qq + 1) : rr * (qq + 1) + (xcd - rr) * qq) + (orig >> 3);
  const int gt = wgid * 4 + w;  // 4 consecutive tiles share the m-strip (A L1 reuse)
  const int mtw = gt / NT, nt = gt - mtw * NT;
  const int m0 = mtw * 64, n0 = nt * 64;

  const unsigned short* ab[4];
  const unsigned short* bb[4];
#pragma unroll
  for (int mf = 0; mf < 4; ++mf) ab[mf] = Apk + ((size_t)(mtw * 4 + mf) * 24 * 64 + l) * 8;
#pragma unroll
  for (int nf = 0; nf < 4; ++nf) bb[nf] = Bpk + ((size_t)(nt * 4 + nf) * 24 * 64 + l) * 8;

  f32x4 acc[4][4];
#pragma unroll
  for (int i = 0; i < 4; ++i)
#pragma unroll
    for (int j = 0; j < 4; ++j) acc[i][j] = (f32x4){0.f, 0.f, 0.f, 0.f};

#pragma unroll
  for (int kt = 0; kt < 24; ++kt) {
    short8 af[4], bfr[4];
#pragma unroll
    for (int mf = 0; mf < 4; ++mf) af[mf] = *(const short8*)(ab[mf] + kt * 512);
#pragma unroll
    for (int nf = 0; nf < 4; ++nf) bfr[nf] = *(const short8*)(bb[nf] + kt * 512);
#pragma unroll
    for (int mf = 0; mf < 4; ++mf)
#pragma unroll
      for (int nf = 0; nf < 4; ++nf)
        acc[mf][nf] = __builtin_amdgcn_mfma_f32_16x16x32_bf16(af[mf], bfr[nf], acc[mf][nf], 0, 0, 0);
  }

  // epilogue: bias + rank-8 LoRA
  float bo[4];
  float4 lb0[4], lb1[4];
#pragma unroll
  for (int nf = 0; nf < 4; ++nf) {
    int o = n0 + nf * 16 + lr;
    bo[nf] = bias[o];
    const float4* lb4 = (const float4*)(lorab + (size_t)o * 8);
    lb0[nf] = lb4[0];
    lb1[nf] = lb4[1];
  }
  const int which = nt / 12;
  const int hh = nt - which * 12;
#pragma unroll
  for (int mf = 0; mf < 4; ++mf) {
#pragma unroll
    for (int v = 0; v < 4; ++v) {
      int m = m0 + mf * 16 + lg * 4 + v;
      const float4* lp4 = (const float4*)(low + (size_t)m * 8);
      float4 l0 = lp4[0], l1 = lp4[1];
      int b = m / 197;
      int n = m - b * 197;
#pragma unroll
      for (int nf = 0; nf < 4; ++nf) {
        float val = acc[mf][nf][v] + bo[nf];
        val += l0.x * lb0[nf].x + l0.y * lb0[nf].y + l0.z * lb0[nf].z + l0.w * lb0[nf].w;
        val += l1.x * lb1[nf].x + l1.y * lb1[nf].y + l1.z * lb1[nf].z + l1.w * lb1[nf].w;
        if (MODE == 0) {
          int hd = nf * 16 + lr;
          int bh = b * 12 + hh;
          unsigned short hv = f2bf(val);
          if (which == 0)      Qg[(bh * 224 + n) * 64 + hd] = hv;
          else if (which == 1) Kg[(bh * 224 + n) * 64 + hd] = hv;
          else                 Vtg[(bh * 64 + hd) * 224 + n] = hv;
        } else {
          outp[(size_t)m * 768 + n0 + nf * 16 + lr] = val;
        }
      }
    }
  }
}

// ---------------- attention: one block per (b,h); writes PACKED aout ----------------
__global__ __launch_bounds__(256) void k_attn(const unsigned short* __restrict__ Qg,
                                              const unsigned short* __restrict__ Kg,
                                              const unsigned short* __restrict__ Vtg,
                                              unsigned short* __restrict__ Apk) {
  __shared__ __align__(16) unsigned short Ps[4][16 * 224];
  const int bh = blockIdx.x;
  const int b = bh / 12, h = bh - b * 12;
  const unsigned short* Qb = Qg + (size_t)bh * (224 * 64);
  const unsigned short* Kb = Kg + (size_t)bh * (224 * 64);
  const unsigned short* Vb = Vtg + (size_t)bh * (64 * 224);
  const int w = threadIdx.x >> 6, l = threadIdx.x & 63;
  const int lr = l & 15, lg = l >> 4;
  for (int t = w; t < 13; t += 4) {
    const int q0 = t * 16;
    short8 aq0 = *(const short8*)(Qb + (q0 + lr) * 64 + lg * 8);
    short8 aq1 = *(const short8*)(Qb + (q0 + lr) * 64 + 32 + lg * 8);
    f32x4 s[14];
#pragma unroll
    for (int jt = 0; jt < 14; ++jt) {
      f32x4 a = (f32x4){0.f, 0.f, 0.f, 0.f};
      short8 bk0 = *(const short8*)(Kb + (jt * 16 + lr) * 64 + lg * 8);
      short8 bk1 = *(const short8*)(Kb + (jt * 16 + lr) * 64 + 32 + lg * 8);
      a = __builtin_amdgcn_mfma_f32_16x16x32_bf16(aq0, bk0, a, 0, 0, 0);
      a = __builtin_amdgcn_mfma_f32_16x16x32_bf16(aq1, bk1, a, 0, 0, 0);
      s[jt] = a;
    }
    float mx[4] = {-3.0e38f, -3.0e38f, -3.0e38f, -3.0e38f};
#pragma unroll
    for (int jt = 0; jt < 14; ++jt) {
      bool valid = (jt * 16 + lr) < 197;
#pragma unroll
      for (int v = 0; v < 4; ++v) {
        float sv = valid ? s[jt][v] : -1.0e30f;
        s[jt][v] = sv;
        mx[v] = fmaxf(mx[v], sv);
      }
    }
#pragma unroll
    for (int v = 0; v < 4; ++v) {
      mx[v] = fmaxf(mx[v], __shfl_xor(mx[v], 1));
      mx[v] = fmaxf(mx[v], __shfl_xor(mx[v], 2));
      mx[v] = fmaxf(mx[v], __shfl_xor(mx[v], 4));
      mx[v] = fmaxf(mx[v], __shfl_xor(mx[v], 8));
    }
    float sum[4] = {0.f, 0.f, 0.f, 0.f};
    const float cc = 0.125f * 1.44269504088896341f;
#pragma unroll
    for (int jt = 0; jt < 14; ++jt)
#pragma unroll
      for (int v = 0; v < 4; ++v) {
        float pv = exp2f((s[jt][v] - mx[v]) * cc);
        s[jt][v] = pv;
        sum[v] += pv;
      }
#pragma unroll
    for (int v = 0; v < 4; ++v) {
      sum[v] += __shfl_xor(sum[v], 1);
      sum[v] += __shfl_xor(sum[v], 2);
      sum[v] += __shfl_xor(sum[v], 4);
      sum[v] += __shfl_xor(sum[v], 8);
    }
    float inv[4];
#pragma unroll
    for (int v = 0; v < 4; ++v) inv[v] = 1.0f / sum[v];
    unsigned short* pw = &Ps[w][0];
#pragma unroll
    for (int jt = 0; jt < 14; ++jt)
#pragma unroll
      for (int v = 0; v < 4; ++v)
        pw[(lg * 4 + v) * 224 + jt * 16 + lr] = f2bf(s[jt][v] * inv[v]);
    f32x4 oacc[4];
#pragma unroll
    for (int jo = 0; jo < 4; ++jo) oacc[jo] = (f32x4){0.f, 0.f, 0.f, 0.f};
#pragma unroll
    for (int kk = 0; kk < 7; ++kk) {
      short8 pa = *(const short8*)(pw + lr * 224 + kk * 32 + lg * 8);
#pragma unroll
      for (int jo = 0; jo < 4; ++jo) {
        short8 bv = *(const short8*)(Vb + (jo * 16 + lr) * 224 + kk * 32 + lg * 8);
        oacc[jo] = __builtin_amdgcn_mfma_f32_16x16x32_bf16(pa, bv, oacc[jo], 0, 0, 0);
      }
    }
    // write PACKED: m = b*197+n, d = h*64 + jo*16 + lr
#pragma unroll
    for (int jo = 0; jo < 4; ++jo) {
      const int kc = h * 2 + (jo >> 1);
      const int lgp = (jo & 1) * 2 + (lr >> 3);
      const int e = lr & 7;
#pragma unroll
      for (int v = 0; v < 4; ++v) {
        int n = q0 + lg * 4 + v;
        if (n < 197) {
          int m = b * 197 + n;
          Apk[((size_t)((m >> 4) * 24 + kc) * 64 + (m & 15) + 16 * lgp) * 8 + e] = f2bf(oacc[jo][v]);
        }
      }
    }
  }
}

extern "C" void kernel_launch(void* const* d_in, const int* in_sizes, int n_in,
                              void* d_out, int out_size, void* d_ws, size_t ws_size,
                              hipStream_t stream) {
  const float* x      = (const float*)d_in[0];
  const float* qkv_w  = (const float*)d_in[1];
  const float* qkv_b  = (const float*)d_in[2];
  const float* qkv_la = (const float*)d_in[3];
  const float* qkv_lb = (const float*)d_in[4];
  const float* out_w  = (const float*)d_in[5];
  const float* out_b  = (const float*)d_in[6];
  const float* out_la = (const float*)d_in[7];
  const float* out_lb = (const float*)d_in[8];
  float* out = (float*)d_out;

  const int M = 64 * 197;  // 12608 = 788*16 = 197*64
  char* p = (char*)d_ws;
  auto carve = [&](size_t bytes) {
    char* r = p;
    p += (bytes + 255) & ~(size_t)255;
    return r;
  };
  unsigned short* Apk  = (unsigned short*)carve((size_t)788 * 24 * 512 * 2);  // packed x / packed aout
  unsigned short* Wqpk = (unsigned short*)carve((size_t)144 * 24 * 512 * 2);
  unsigned short* Wopk = (unsigned short*)carve((size_t)48 * 24 * 512 * 2);
  float* lowq          = (float*)carve((size_t)M * 8 * 4);
  float* lowo          = (float*)carve((size_t)M * 8 * 4);
  unsigned short* Qg   = (unsigned short*)carve((size_t)768 * 224 * 64 * 2);
  unsigned short* Kg   = (unsigned short*)carve((size_t)768 * 224 * 64 * 2);
  unsigned short* Vtg  = (unsigned short*)carve((size_t)768 * 64 * 224 * 2);

  k_pack_w<<<864, 256, 0, stream>>>(qkv_w, Wqpk, 144 * 24);
  k_pack_w<<<288, 256, 0, stream>>>(out_w, Wopk, 48 * 24);
  k_zpad<<<(768 * 64 * 27 + 255) / 256, 256, 0, stream>>>(Vtg);
  k_pxl<<<788, 256, 0, stream>>>(x, qkv_la, Apk, lowq);
  // qkv: 197 m-strips * 36 n-strips = 7092 wave-tiles / 4
  k_gd_qkv_or_out<0, 36><<<1773, 256, 0, stream>>>(Apk, Wqpk, qkv_b, lowq, qkv_lb, Qg, Kg, Vtg, nullptr);
  k_attn<<<768, 256, 0, stream>>>(Qg, Kg, Vtg, Apk);  // Apk now holds packed attn-out (x is dead)
  k_low_pk<<<(M + 3) / 4, 256, 0, stream>>>(Apk, out_la, lowo, M);
  // out: 197 * 12 = 2364 wave-tiles / 4
  k_gd_qkv_or_out<1, 12><<<591, 256, 0, stream>>>(Apk, Wopk, out_b, lowo, out_lb, nullptr, nullptr, nullptr, out);
}

// Round 7
// 244.935 us; speedup vs baseline: 1.5094x; 1.1128x over previous
//
#include <hip/hip_runtime.h>
#include <stdint.h>

typedef __attribute__((ext_vector_type(8))) short short8;
typedef __attribute__((ext_vector_type(4))) float f32x4;

__device__ __forceinline__ unsigned short f2bf(float f) {
  unsigned u = __float_as_uint(f);
  u += 0x7FFF + ((u >> 16) & 1);
  return (unsigned short)(u >> 16);
}
__device__ __forceinline__ float bf2f(unsigned short h) {
  return __uint_as_float(((unsigned)h) << 16);
}

// Packed fragment layout (k-major) for mfma_f32_16x16x32_bf16 operands:
// frag tile (rt, kc) covers rows [rt*16,rt*16+16) x k [kc*32,kc*32+32).
// byte offset = (kc*NRT + rt)*1024 + lane*16, lane = (row&15) + 16*((k&31)>>3), elem = k&7.
// One fragment load = per-lane 16B, wave-contiguous 1KB burst.

// ---------------- prep: pack qkv_w + out_w (f32 -> packed bf16) + zero V pads ----------------
__global__ __launch_bounds__(256) void k_prep(const float* __restrict__ qkv_w,
                                              const float* __restrict__ out_w,
                                              unsigned short* __restrict__ Wq,
                                              unsigned short* __restrict__ Wo,
                                              unsigned short* __restrict__ vt) {
  int bid = blockIdx.x;
  if (bid < 864 + 288) {
    const float* W = (bid < 864) ? qkv_w : out_w;
    unsigned short* dst = (bid < 864) ? Wq : Wo;
    const int NRT = (bid < 864) ? 144 : 48;
    int base = (bid < 864) ? 0 : 864;
    int wv = ((bid - base) * 256 + threadIdx.x) >> 6;
    int l = threadIdx.x & 63;
    int rt = wv / 24, kc = wv - rt * 24;
    int lr = l & 15, lg = l >> 4;
    const float* src = W + (size_t)(rt * 16 + lr) * 768 + kc * 32 + lg * 8;
    float4 a = *(const float4*)src;
    float4 b = *(const float4*)(src + 4);
    short8 o;
    o[0] = f2bf(a.x); o[1] = f2bf(a.y); o[2] = f2bf(a.z); o[3] = f2bf(a.w);
    o[4] = f2bf(b.x); o[5] = f2bf(b.y); o[6] = f2bf(b.z); o[7] = f2bf(b.w);
    *(short8*)(dst + (size_t)(kc * NRT + rt) * 512 + l * 8) = o;
  } else {
    const int TOT = 768 * 64 * 27;
    int i = (bid - 1152) * 256 + threadIdx.x;
    if (i < TOT) {
      int row = i / 27, c = i - row * 27;
      vt[row * 224 + 197 + c] = 0;
    }
  }
}

// ---------------- fused: pack x (f32 -> packed bf16) + low = 2*X@A^T ----------------
// one block = one 16-row m-tile (M = 788*16 exactly)
__global__ __launch_bounds__(256) void k_pxl(const float* __restrict__ x,
                                             const float* __restrict__ lora_a,
                                             unsigned short* __restrict__ Apk,
                                             float* __restrict__ low) {
  __shared__ unsigned short xs[16 * 776];
  __shared__ float As[8 * 768];
  const int t = threadIdx.x;
  const int mt = blockIdx.x;
  const float4* x4 = (const float4*)(x + (size_t)mt * 16 * 768);
#pragma unroll
  for (int i = 0; i < 12; ++i) {
    float4 v = x4[i * 256 + t];
    int e0 = (i * 256 + t) * 4;
    int row = e0 / 768, col = e0 - row * 768;
    unsigned short* d = &xs[row * 776 + col];
    d[0] = f2bf(v.x); d[1] = f2bf(v.y); d[2] = f2bf(v.z); d[3] = f2bf(v.w);
  }
  for (int i = t; i < 1536; i += 256) ((float4*)As)[i] = ((const float4*)lora_a)[i];
  __syncthreads();
  const int w = t >> 6, l = t & 63;
  float acc[4][8];
#pragma unroll
  for (int r = 0; r < 4; ++r)
#pragma unroll
    for (int k = 0; k < 8; ++k) acc[r][k] = 0.f;
  for (int j = 0; j < 12; ++j) {
    int d = j * 64 + l;
#pragma unroll
    for (int r = 0; r < 4; ++r) {
      float xv = bf2f(xs[(w * 4 + r) * 776 + d]);
#pragma unroll
      for (int k = 0; k < 8; ++k) acc[r][k] += xv * As[k * 768 + d];
    }
  }
#pragma unroll
  for (int r = 0; r < 4; ++r)
#pragma unroll
    for (int k = 0; k < 8; ++k) {
      float a = acc[r][k];
      for (int dd = 1; dd < 64; dd <<= 1) a += __shfl_xor(a, dd);
      if (l == 0) low[((size_t)mt * 16 + w * 4 + r) * 8 + k] = 2.0f * a;
    }
  const int lr = l & 15, lg = l >> 4;
#pragma unroll
  for (int kk = 0; kk < 6; ++kk) {
    int kc = w * 6 + kk;
    short8 v = *(const short8*)(&xs[lr * 776 + kc * 32 + lg * 8]);
    *(short8*)(Apk + (size_t)(kc * 788 + mt) * 512 + l * 8) = v;
  }
}

// ---------------- rank-8 LoRA low from PACKED (k-major) bf16 input ----------------
__global__ __launch_bounds__(256) void k_low_pk(const unsigned short* __restrict__ Apk,
                                                const float* __restrict__ lora_a,
                                                float* __restrict__ low, int M) {
  __shared__ float As[8 * 768];
  for (int i = threadIdx.x; i < 1536; i += 256) ((float4*)As)[i] = ((const float4*)lora_a)[i];
  __syncthreads();
  int w = threadIdx.x >> 6, l = threadIdx.x & 63;
  int m = blockIdx.x * 4 + w;
  if (m >= M) return;
  const int mt = m >> 4, mr = m & 15;
  const int kcb = l >> 5, lgp = (l & 31) >> 3, e = l & 7;
  float acc[8] = {0, 0, 0, 0, 0, 0, 0, 0};
  for (int j = 0; j < 12; ++j) {
    int d = j * 64 + l;
    float xv = bf2f(Apk[((size_t)((j * 2 + kcb) * 788 + mt) * 64 + mr + 16 * lgp) * 8 + e]);
#pragma unroll
    for (int r = 0; r < 8; ++r) acc[r] += xv * As[r * 768 + d];
  }
#pragma unroll
  for (int r = 0; r < 8; ++r) {
    for (int dd = 1; dd < 64; dd <<= 1) acc[r] += __shfl_xor(acc[r], dd);
    if (l == 0) low[(size_t)m * 8 + r] = 2.0f * acc[r];
  }
}

// ---------------- pipelined packed-fragment GEMM: 1 wave = 64x64, no LDS/barriers ----------------
// MODE 0: qkv (NT=36, NRTB=144) scatter to Q/K/Vt. MODE 1: out (NT=12, NRTB=48) f32 out.
template <int MODE, int NT, int NRTB>
__global__ __launch_bounds__(256, 3) void k_gp(
    const unsigned short* __restrict__ Apk, const unsigned short* __restrict__ Bpk,
    const float* __restrict__ bias, const float* __restrict__ low,
    const float* __restrict__ lorab, unsigned short* __restrict__ Qg,
    unsigned short* __restrict__ Kg, unsigned short* __restrict__ Vtg,
    float* __restrict__ outp) {
  const int w = threadIdx.x >> 6, l = threadIdx.x & 63;
  const int lr = l & 15, lg = l >> 4;
  const int nwg = gridDim.x;
  const int orig = blockIdx.x;
  const int qq = nwg >> 3, rr = nwg & 7, xcd = orig & 7;
  const int wgid = (xcd < rr ? xcd * (qq + 1) : rr * (qq + 1) + (xcd - rr) * qq) + (orig >> 3);
  const int gt = wgid * 4 + w;  // 4 waves of a block share the m-strip (A L1 reuse)
  const int mtw = gt / NT, nt = gt - mtw * NT;
  const int m0 = mtw * 64, n0 = nt * 64;

  const int KSA = 788 * 512;   // shorts per kt plane (A)
  const int KSB = NRTB * 512;  // shorts per kt plane (B)
  const unsigned short* pa = Apk + (size_t)(mtw * 4) * 512 + l * 8;
  const unsigned short* pb = Bpk + (size_t)(nt * 4) * 512 + l * 8;

  f32x4 acc[4][4];
#pragma unroll
  for (int i = 0; i < 4; ++i)
#pragma unroll
    for (int j = 0; j < 4; ++j) acc[i][j] = (f32x4){0.f, 0.f, 0.f, 0.f};

  short8 a0[4], b0[4], a1[4], b1[4];
#define LD4(dst, p) \
  { dst[0] = *(const short8*)(p); dst[1] = *(const short8*)((p) + 512); \
    dst[2] = *(const short8*)((p) + 1024); dst[3] = *(const short8*)((p) + 1536); }
#define MFMA16(af, bf) \
  _Pragma("unroll") for (int mf = 0; mf < 4; ++mf) \
  _Pragma("unroll") for (int nf = 0; nf < 4; ++nf) \
    acc[mf][nf] = __builtin_amdgcn_mfma_f32_16x16x32_bf16(af[mf], bf[nf], acc[mf][nf], 0, 0, 0);

  LD4(a0, pa);
  LD4(b0, pb);
#pragma unroll
  for (int k2 = 0; k2 < 12; ++k2) {
    // prefetch kt+1 (always exists: kt = 2*k2 <= 22)
    LD4(a1, pa + KSA);
    LD4(b1, pb + KSB);
    __builtin_amdgcn_s_setprio(1);
    MFMA16(a0, b0);
    __builtin_amdgcn_s_setprio(0);
    pa += 2 * KSA;
    pb += 2 * KSB;
    if (k2 < 11) {  // prefetch kt+2
      LD4(a0, pa);
      LD4(b0, pb);
    }
    __builtin_amdgcn_s_setprio(1);
    MFMA16(a1, b1);
    __builtin_amdgcn_s_setprio(0);
  }
#undef LD4
#undef MFMA16

  // epilogue: bias + rank-8 LoRA
  float bo[4];
  float4 lb0[4], lb1[4];
#pragma unroll
  for (int nf = 0; nf < 4; ++nf) {
    int o = n0 + nf * 16 + lr;
    bo[nf] = bias[o];
    const float4* lb4 = (const float4*)(lorab + (size_t)o * 8);
    lb0[nf] = lb4[0];
    lb1[nf] = lb4[1];
  }
  const int which = nt / 12;
  const int hh = nt - which * 12;
#pragma unroll
  for (int mf = 0; mf < 4; ++mf) {
#pragma unroll
    for (int v = 0; v < 4; ++v) {
      int m = m0 + mf * 16 + lg * 4 + v;
      const float4* lp4 = (const float4*)(low + (size_t)m * 8);
      float4 l0 = lp4[0], l1 = lp4[1];
      int b = m / 197;
      int n = m - b * 197;
#pragma unroll
      for (int nf = 0; nf < 4; ++nf) {
        float val = acc[mf][nf][v] + bo[nf];
        val += l0.x * lb0[nf].x + l0.y * lb0[nf].y + l0.z * lb0[nf].z + l0.w * lb0[nf].w;
        val += l1.x * lb1[nf].x + l1.y * lb1[nf].y + l1.z * lb1[nf].z + l1.w * lb1[nf].w;
        if (MODE == 0) {
          int hd = nf * 16 + lr;
          int bh = b * 12 + hh;
          unsigned short hv = f2bf(val);
          if (which == 0)      Qg[(bh * 224 + n) * 64 + hd] = hv;
          else if (which == 1) Kg[(bh * 224 + n) * 64 + hd] = hv;
          else                 Vtg[(bh * 64 + hd) * 224 + n] = hv;
        } else {
          outp[(size_t)m * 768 + n0 + nf * 16 + lr] = val;
        }
      }
    }
  }
}

// ---------------- attention: one block per (b,h); writes PACKED (k-major) aout ----------------
__global__ __launch_bounds__(256) void k_attn(const unsigned short* __restrict__ Qg,
                                              const unsigned short* __restrict__ Kg,
                                              const unsigned short* __restrict__ Vtg,
                                              unsigned short* __restrict__ Apk) {
  __shared__ __align__(16) unsigned short Ps[4][16 * 224];
  const int bh = blockIdx.x;
  const int b = bh / 12, h = bh - b * 12;
  const unsigned short* Qb = Qg + (size_t)bh * (224 * 64);
  const unsigned short* Kb = Kg + (size_t)bh * (224 * 64);
  const unsigned short* Vb = Vtg + (size_t)bh * (64 * 224);
  const int w = threadIdx.x >> 6, l = threadIdx.x & 63;
  const int lr = l & 15, lg = l >> 4;
  for (int t = w; t < 13; t += 4) {
    const int q0 = t * 16;
    short8 aq0 = *(const short8*)(Qb + (q0 + lr) * 64 + lg * 8);
    short8 aq1 = *(const short8*)(Qb + (q0 + lr) * 64 + 32 + lg * 8);
    f32x4 s[14];
#pragma unroll
    for (int jt = 0; jt < 14; ++jt) {
      f32x4 a = (f32x4){0.f, 0.f, 0.f, 0.f};
      short8 bk0 = *(const short8*)(Kb + (jt * 16 + lr) * 64 + lg * 8);
      short8 bk1 = *(const short8*)(Kb + (jt * 16 + lr) * 64 + 32 + lg * 8);
      a = __builtin_amdgcn_mfma_f32_16x16x32_bf16(aq0, bk0, a, 0, 0, 0);
      a = __builtin_amdgcn_mfma_f32_16x16x32_bf16(aq1, bk1, a, 0, 0, 0);
      s[jt] = a;
    }
    float mx[4] = {-3.0e38f, -3.0e38f, -3.0e38f, -3.0e38f};
#pragma unroll
    for (int jt = 0; jt < 14; ++jt) {
      bool valid = (jt * 16 + lr) < 197;
#pragma unroll
      for (int v = 0; v < 4; ++v) {
        float sv = valid ? s[jt][v] : -1.0e30f;
        s[jt][v] = sv;
        mx[v] = fmaxf(mx[v], sv);
      }
    }
#pragma unroll
    for (int v = 0; v < 4; ++v) {
      mx[v] = fmaxf(mx[v], __shfl_xor(mx[v], 1));
      mx[v] = fmaxf(mx[v], __shfl_xor(mx[v], 2));
      mx[v] = fmaxf(mx[v], __shfl_xor(mx[v], 4));
      mx[v] = fmaxf(mx[v], __shfl_xor(mx[v], 8));
    }
    float sum[4] = {0.f, 0.f, 0.f, 0.f};
    const float cc = 0.125f * 1.44269504088896341f;
#pragma unroll
    for (int jt = 0; jt < 14; ++jt)
#pragma unroll
      for (int v = 0; v < 4; ++v) {
        float pv = exp2f((s[jt][v] - mx[v]) * cc);
        s[jt][v] = pv;
        sum[v] += pv;
      }
#pragma unroll
    for (int v = 0; v < 4; ++v) {
      sum[v] += __shfl_xor(sum[v], 1);
      sum[v] += __shfl_xor(sum[v], 2);
      sum[v] += __shfl_xor(sum[v], 4);
      sum[v] += __shfl_xor(sum[v], 8);
    }
    float inv[4];
#pragma unroll
    for (int v = 0; v < 4; ++v) inv[v] = 1.0f / sum[v];
    unsigned short* pw = &Ps[w][0];
#pragma unroll
    for (int jt = 0; jt < 14; ++jt)
#pragma unroll
      for (int v = 0; v < 4; ++v)
        pw[(lg * 4 + v) * 224 + jt * 16 + lr] = f2bf(s[jt][v] * inv[v]);
    f32x4 oacc[4];
#pragma unroll
    for (int jo = 0; jo < 4; ++jo) oacc[jo] = (f32x4){0.f, 0.f, 0.f, 0.f};
#pragma unroll
    for (int kk = 0; kk < 7; ++kk) {
      short8 pa = *(const short8*)(pw + lr * 224 + kk * 32 + lg * 8);
#pragma unroll
      for (int jo = 0; jo < 4; ++jo) {
        short8 bv = *(const short8*)(Vb + (jo * 16 + lr) * 224 + kk * 32 + lg * 8);
        oacc[jo] = __builtin_amdgcn_mfma_f32_16x16x32_bf16(pa, bv, oacc[jo], 0, 0, 0);
      }
    }
    // write PACKED k-major: m = b*197+n, d = h*64 + jo*16 + lr
#pragma unroll
    for (int jo = 0; jo < 4; ++jo) {
      const int kc = h * 2 + (jo >> 1);
      const int lgp = (jo & 1) * 2 + (lr >> 3);
      const int e = lr & 7;
#pragma unroll
      for (int v = 0; v < 4; ++v) {
        int n = q0 + lg * 4 + v;
        if (n < 197) {
          int m = b * 197 + n;
          Apk[((size_t)(kc * 788 + (m >> 4)) * 64 + (m & 15) + 16 * lgp) * 8 + e] = f2bf(oacc[jo][v]);
        }
      }
    }
  }
}

extern "C" void kernel_launch(void* const* d_in, const int* in_sizes, int n_in,
                              void* d_out, int out_size, void* d_ws, size_t ws_size,
                              hipStream_t stream) {
  const float* x      = (const float*)d_in[0];
  const float* qkv_w  = (const float*)d_in[1];
  const float* qkv_b  = (const float*)d_in[2];
  const float* qkv_la = (const float*)d_in[3];
  const float* qkv_lb = (const float*)d_in[4];
  const float* out_w  = (const float*)d_in[5];
  const float* out_b  = (const float*)d_in[6];
  const float* out_la = (const float*)d_in[7];
  const float* out_lb = (const float*)d_in[8];
  float* out = (float*)d_out;

  const int M = 64 * 197;  // 12608 = 788*16 = 197*64
  char* p = (char*)d_ws;
  auto carve = [&](size_t bytes) {
    char* r = p;
    p += (bytes + 255) & ~(size_t)255;
    return r;
  };
  unsigned short* Apk  = (unsigned short*)carve((size_t)788 * 24 * 512 * 2);  // packed x / packed aout
  unsigned short* Wqpk = (unsigned short*)carve((size_t)144 * 24 * 512 * 2);
  unsigned short* Wopk = (unsigned short*)carve((size_t)48 * 24 * 512 * 2);
  float* lowq          = (float*)carve((size_t)M * 8 * 4);
  float* lowo          = (float*)carve((size_t)M * 8 * 4);
  unsigned short* Qg   = (unsigned short*)carve((size_t)768 * 224 * 64 * 2);
  unsigned short* Kg   = (unsigned short*)carve((size_t)768 * 224 * 64 * 2);
  unsigned short* Vtg  = (unsigned short*)carve((size_t)768 * 64 * 224 * 2);

  // 864 (pack qkv_w) + 288 (pack out_w) + 5184 (zero V pads)
  k_prep<<<6336, 256, 0, stream>>>(qkv_w, out_w, Wqpk, Wopk, Vtg);
  k_pxl<<<788, 256, 0, stream>>>(x, qkv_la, Apk, lowq);
  k_gp<0, 36, 144><<<1773, 256, 0, stream>>>(Apk, Wqpk, qkv_b, lowq, qkv_lb, Qg, Kg, Vtg, nullptr);
  k_attn<<<768, 256, 0, stream>>>(Qg, Kg, Vtg, Apk);  // Apk now holds packed attn-out
  k_low_pk<<<(M + 3) / 4, 256, 0, stream>>>(Apk, out_la, lowo, M);
  k_gp<1, 12, 48><<<591, 256, 0, stream>>>(Apk, Wopk, out_b, lowo, out_lb, nullptr, nullptr, nullptr, out);
}

// Round 8
// 241.682 us; speedup vs baseline: 1.5297x; 1.0135x over previous
//
#include <hip/hip_runtime.h>
#include <stdint.h>

typedef __attribute__((ext_vector_type(8))) short short8;
typedef __attribute__((ext_vector_type(4))) float f32x4;

__device__ __forceinline__ unsigned short f2bf(float f) {
  unsigned u = __float_as_uint(f);
  u += 0x7FFF + ((u >> 16) & 1);
  return (unsigned short)(u >> 16);
}
__device__ __forceinline__ float bf2f(unsigned short h) {
  return __uint_as_float(((unsigned)h) << 16);
}

// Packed fragment layout (k-major) for mfma_f32_16x16x32_bf16 operands:
// frag tile (rt, kc): byte off = (kc*NRT + rt)*1024 + lane*16,
// lane = (row&15) + 16*((k&31)>>3), elem = k&7. 1 frag = wave-contiguous 1KB.

// ---------------- merged prep: pack x + low (blocks 0..787), pack weights, zero V pads ----------------
__global__ __launch_bounds__(256) void k_prep2(const float* __restrict__ x,
                                               const float* __restrict__ lora_a,
                                               const float* __restrict__ qkv_w,
                                               const float* __restrict__ out_w,
                                               unsigned short* __restrict__ Apk,
                                               float* __restrict__ low,
                                               unsigned short* __restrict__ Wq,
                                               unsigned short* __restrict__ Wo,
                                               unsigned short* __restrict__ vt) {
  __shared__ unsigned short xs[16 * 776];
  __shared__ float As[8 * 768];
  const int bid = blockIdx.x;
  const int t = threadIdx.x;
  if (bid < 788) {
    // ---- pack x tile + rank-8 low ----
    const int mt = bid;
    const float4* x4 = (const float4*)(x + (size_t)mt * 16 * 768);
#pragma unroll
    for (int i = 0; i < 12; ++i) {
      float4 v = x4[i * 256 + t];
      int e0 = (i * 256 + t) * 4;
      int row = e0 / 768, col = e0 - row * 768;
      unsigned short* d = &xs[row * 776 + col];
      d[0] = f2bf(v.x); d[1] = f2bf(v.y); d[2] = f2bf(v.z); d[3] = f2bf(v.w);
    }
    for (int i = t; i < 1536; i += 256) ((float4*)As)[i] = ((const float4*)lora_a)[i];
    __syncthreads();
    const int w = t >> 6, l = t & 63;
    float acc[4][8];
#pragma unroll
    for (int r = 0; r < 4; ++r)
#pragma unroll
      for (int k = 0; k < 8; ++k) acc[r][k] = 0.f;
    for (int j = 0; j < 12; ++j) {
      int d = j * 64 + l;
#pragma unroll
      for (int r = 0; r < 4; ++r) {
        float xv = bf2f(xs[(w * 4 + r) * 776 + d]);
#pragma unroll
        for (int k = 0; k < 8; ++k) acc[r][k] += xv * As[k * 768 + d];
      }
    }
#pragma unroll
    for (int r = 0; r < 4; ++r)
#pragma unroll
      for (int k = 0; k < 8; ++k) {
        float a = acc[r][k];
        for (int dd = 1; dd < 64; dd <<= 1) a += __shfl_xor(a, dd);
        if (l == 0) low[((size_t)mt * 16 + w * 4 + r) * 8 + k] = 2.0f * a;
      }
    const int lr = l & 15, lg = l >> 4;
#pragma unroll
    for (int kk = 0; kk < 6; ++kk) {
      int kc = w * 6 + kk;
      short8 v = *(const short8*)(&xs[lr * 776 + kc * 32 + lg * 8]);
      *(short8*)(Apk + (size_t)(kc * 788 + mt) * 512 + l * 8) = v;
    }
  } else if (bid < 1940) {
    // ---- pack weights ----
    const bool isq = bid < 1652;
    const float* W = isq ? qkv_w : out_w;
    unsigned short* dst = isq ? Wq : Wo;
    const int NRT = isq ? 144 : 48;
    const int base = isq ? 788 : 1652;
    int wv = ((bid - base) * 256 + t) >> 6;
    int l = t & 63;
    int rt = wv / 24, kc = wv - rt * 24;
    int lr = l & 15, lg = l >> 4;
    const float* src = W + (size_t)(rt * 16 + lr) * 768 + kc * 32 + lg * 8;
    float4 a = *(const float4*)src;
    float4 b = *(const float4*)(src + 4);
    short8 o;
    o[0] = f2bf(a.x); o[1] = f2bf(a.y); o[2] = f2bf(a.z); o[3] = f2bf(a.w);
    o[4] = f2bf(b.x); o[5] = f2bf(b.y); o[6] = f2bf(b.z); o[7] = f2bf(b.w);
    *(short8*)(dst + (size_t)(kc * NRT + rt) * 512 + l * 8) = o;
  } else {
    // ---- zero V seq-pad: one thread per (bh,hd) row ----
    int r = (bid - 1940) * 256 + t;  // [0, 49152)
    unsigned short* d = vt + (size_t)r * 224 + 197;
#pragma unroll
    for (int c = 0; c < 27; ++c) d[c] = 0;
  }
}

// ---------------- rank-8 LoRA low from PACKED (k-major) bf16 input ----------------
__global__ __launch_bounds__(256) void k_low_pk(const unsigned short* __restrict__ Apk,
                                                const float* __restrict__ lora_a,
                                                float* __restrict__ low, int M) {
  __shared__ float As[8 * 768];
  for (int i = threadIdx.x; i < 1536; i += 256) ((float4*)As)[i] = ((const float4*)lora_a)[i];
  __syncthreads();
  int w = threadIdx.x >> 6, l = threadIdx.x & 63;
  int m = blockIdx.x * 4 + w;
  if (m >= M) return;
  const int mt = m >> 4, mr = m & 15;
  const int kcb = l >> 5, lgp = (l & 31) >> 3, e = l & 7;
  float acc[8] = {0, 0, 0, 0, 0, 0, 0, 0};
  for (int j = 0; j < 12; ++j) {
    int d = j * 64 + l;
    float xv = bf2f(Apk[((size_t)((j * 2 + kcb) * 788 + mt) * 64 + mr + 16 * lgp) * 8 + e]);
#pragma unroll
    for (int r = 0; r < 8; ++r) acc[r] += xv * As[r * 768 + d];
  }
#pragma unroll
  for (int r = 0; r < 8; ++r) {
    for (int dd = 1; dd < 64; dd <<= 1) acc[r] += __shfl_xor(acc[r], dd);
    if (l == 0) low[(size_t)m * 8 + r] = 2.0f * acc[r];
  }
}

// ---------------- pipelined packed-fragment GEMM, shared-B blocks ----------------
// Block = 4 waves: same n-strip (B frags L1-shared), 4 adjacent m-strips.
// 50 m-groups (m-strips 0..199, clamped to 196). Grid = 50*NT.
// MODE 0: qkv (NT=36, NRTB=144) scatter to Q/K/Vt. MODE 1: out (NT=12, NRTB=48).
template <int MODE, int NT, int NRTB>
__global__ __launch_bounds__(256, 3) void k_gp2(
    const unsigned short* __restrict__ Apk, const unsigned short* __restrict__ Bpk,
    const float* __restrict__ bias, const float* __restrict__ low,
    const float* __restrict__ lorab, unsigned short* __restrict__ Qg,
    unsigned short* __restrict__ Kg, unsigned short* __restrict__ Vtg,
    float* __restrict__ outp) {
  const int w = threadIdx.x >> 6, l = threadIdx.x & 63;
  const int lr = l & 15, lg = l >> 4;
  const int nwg = gridDim.x;
  const int orig = blockIdx.x;
  const int qq = nwg >> 3, rr = nwg & 7, xcd = orig & 7;
  const int wgid = (xcd < rr ? xcd * (qq + 1) : rr * (qq + 1) + (xcd - rr) * qq) + (orig >> 3);
  const int mg = wgid / NT, nt = wgid - mg * NT;  // nt fastest: A-panel L2-hot across 36 blocks
  int mtw = mg * 4 + w;
  if (mtw > 196) mtw = 196;  // duplicate waves write identical data (benign)
  const int m0 = mtw * 64, n0 = nt * 64;

  const size_t KSA = 788 * 512;   // shorts per kt plane (A)
  const size_t KSB = NRTB * 512;  // shorts per kt plane (B)
  const unsigned short* pa = Apk + (size_t)(mtw * 4) * 512 + l * 8;
  const unsigned short* pb = Bpk + (size_t)(nt * 4) * 512 + l * 8;

  f32x4 acc[4][4];
#pragma unroll
  for (int i = 0; i < 4; ++i)
#pragma unroll
    for (int j = 0; j < 4; ++j) acc[i][j] = (f32x4){0.f, 0.f, 0.f, 0.f};

  short8 ab[2][4], bb[2][4];
#define LDA4(dst, kt) \
  { const unsigned short* q_ = pa + (size_t)(kt) * KSA; \
    dst[0] = *(const short8*)(q_); dst[1] = *(const short8*)(q_ + 512); \
    dst[2] = *(const short8*)(q_ + 1024); dst[3] = *(const short8*)(q_ + 1536); }
#define LDB4(dst, kt) \
  { const unsigned short* q_ = pb + (size_t)(kt) * KSB; \
    dst[0] = *(const short8*)(q_); dst[1] = *(const short8*)(q_ + 512); \
    dst[2] = *(const short8*)(q_ + 1024); dst[3] = *(const short8*)(q_ + 1536); }
#define MFMA16(af, bf) \
  _Pragma("unroll") for (int mf = 0; mf < 4; ++mf) \
  _Pragma("unroll") for (int nf = 0; nf < 4; ++nf) \
    acc[mf][nf] = __builtin_amdgcn_mfma_f32_16x16x32_bf16(af[mf], bf[nf], acc[mf][nf], 0, 0, 0);

  LDB4(bb[0], 0);
  LDA4(ab[0], 0);
#pragma unroll
  for (int kt = 0; kt < 24; ++kt) {
    const int cur = kt & 1, nxt = cur ^ 1;
    if (kt + 1 < 24) {
      LDB4(bb[nxt], kt + 1);
      LDA4(ab[nxt], kt + 1);
    }
    __builtin_amdgcn_s_setprio(1);
    MFMA16(ab[cur], bb[cur]);
    __builtin_amdgcn_s_setprio(0);
  }
#undef LDA4
#undef LDB4
#undef MFMA16

  // epilogue: bias + rank-8 LoRA
  float bo[4];
  float4 lb0[4], lb1[4];
#pragma unroll
  for (int nf = 0; nf < 4; ++nf) {
    int o = n0 + nf * 16 + lr;
    bo[nf] = bias[o];
    const float4* lb4 = (const float4*)(lorab + (size_t)o * 8);
    lb0[nf] = lb4[0];
    lb1[nf] = lb4[1];
  }
  const int which = nt / 12;
  const int hh = nt - which * 12;
#pragma unroll
  for (int mf = 0; mf < 4; ++mf) {
#pragma unroll
    for (int v = 0; v < 4; ++v) {
      int m = m0 + mf * 16 + lg * 4 + v;
      const float4* lp4 = (const float4*)(low + (size_t)m * 8);
      float4 l0 = lp4[0], l1 = lp4[1];
      int b = m / 197;
      int n = m - b * 197;
#pragma unroll
      for (int nf = 0; nf < 4; ++nf) {
        float val = acc[mf][nf][v] + bo[nf];
        val += l0.x * lb0[nf].x + l0.y * lb0[nf].y + l0.z * lb0[nf].z + l0.w * lb0[nf].w;
        val += l1.x * lb1[nf].x + l1.y * lb1[nf].y + l1.z * lb1[nf].z + l1.w * lb1[nf].w;
        if (MODE == 0) {
          int hd = nf * 16 + lr;
          int bh = b * 12 + hh;
          unsigned short hv = f2bf(val);
          if (which == 0)      Qg[(bh * 224 + n) * 64 + hd] = hv;
          else if (which == 1) Kg[(bh * 224 + n) * 64 + hd] = hv;
          else                 Vtg[(bh * 64 + hd) * 224 + n] = hv;
        } else {
          outp[(size_t)m * 768 + n0 + nf * 16 + lr] = val;
        }
      }
    }
  }
}

// ---------------- attention: one block per (b,h); writes PACKED (k-major) aout ----------------
__global__ __launch_bounds__(256) void k_attn(const unsigned short* __restrict__ Qg,
                                              const unsigned short* __restrict__ Kg,
                                              const unsigned short* __restrict__ Vtg,
                                              unsigned short* __restrict__ Apk) {
  __shared__ __align__(16) unsigned short Ps[4][16 * 224];
  const int bh = blockIdx.x;
  const int b = bh / 12, h = bh - b * 12;
  const unsigned short* Qb = Qg + (size_t)bh * (224 * 64);
  const unsigned short* Kb = Kg + (size_t)bh * (224 * 64);
  const unsigned short* Vb = Vtg + (size_t)bh * (64 * 224);
  const int w = threadIdx.x >> 6, l = threadIdx.x & 63;
  const int lr = l & 15, lg = l >> 4;
  for (int t = w; t < 13; t += 4) {
    const int q0 = t * 16;
    short8 aq0 = *(const short8*)(Qb + (q0 + lr) * 64 + lg * 8);
    short8 aq1 = *(const short8*)(Qb + (q0 + lr) * 64 + 32 + lg * 8);
    f32x4 s[14];
#pragma unroll
    for (int jt = 0; jt < 14; ++jt) {
      f32x4 a = (f32x4){0.f, 0.f, 0.f, 0.f};
      short8 bk0 = *(const short8*)(Kb + (jt * 16 + lr) * 64 + lg * 8);
      short8 bk1 = *(const short8*)(Kb + (jt * 16 + lr) * 64 + 32 + lg * 8);
      a = __builtin_amdgcn_mfma_f32_16x16x32_bf16(aq0, bk0, a, 0, 0, 0);
      a = __builtin_amdgcn_mfma_f32_16x16x32_bf16(aq1, bk1, a, 0, 0, 0);
      s[jt] = a;
    }
    float mx[4] = {-3.0e38f, -3.0e38f, -3.0e38f, -3.0e38f};
#pragma unroll
    for (int jt = 0; jt < 14; ++jt) {
      bool valid = (jt * 16 + lr) < 197;
#pragma unroll
      for (int v = 0; v < 4; ++v) {
        float sv = valid ? s[jt][v] : -1.0e30f;
        s[jt][v] = sv;
        mx[v] = fmaxf(mx[v], sv);
      }
    }
#pragma unroll
    for (int v = 0; v < 4; ++v) {
      mx[v] = fmaxf(mx[v], __shfl_xor(mx[v], 1));
      mx[v] = fmaxf(mx[v], __shfl_xor(mx[v], 2));
      mx[v] = fmaxf(mx[v], __shfl_xor(mx[v], 4));
      mx[v] = fmaxf(mx[v], __shfl_xor(mx[v], 8));
    }
    float sum[4] = {0.f, 0.f, 0.f, 0.f};
    const float cc = 0.125f * 1.44269504088896341f;
#pragma unroll
    for (int jt = 0; jt < 14; ++jt)
#pragma unroll
      for (int v = 0; v < 4; ++v) {
        float pv = exp2f((s[jt][v] - mx[v]) * cc);
        s[jt][v] = pv;
        sum[v] += pv;
      }
#pragma unroll
    for (int v = 0; v < 4; ++v) {
      sum[v] += __shfl_xor(sum[v], 1);
      sum[v] += __shfl_xor(sum[v], 2);
      sum[v] += __shfl_xor(sum[v], 4);
      sum[v] += __shfl_xor(sum[v], 8);
    }
    float inv[4];
#pragma unroll
    for (int v = 0; v < 4; ++v) inv[v] = 1.0f / sum[v];
    unsigned short* pw = &Ps[w][0];
#pragma unroll
    for (int jt = 0; jt < 14; ++jt)
#pragma unroll
      for (int v = 0; v < 4; ++v)
        pw[(lg * 4 + v) * 224 + jt * 16 + lr] = f2bf(s[jt][v] * inv[v]);
    f32x4 oacc[4];
#pragma unroll
    for (int jo = 0; jo < 4; ++jo) oacc[jo] = (f32x4){0.f, 0.f, 0.f, 0.f};
#pragma unroll
    for (int kk = 0; kk < 7; ++kk) {
      short8 pa = *(const short8*)(pw + lr * 224 + kk * 32 + lg * 8);
#pragma unroll
      for (int jo = 0; jo < 4; ++jo) {
        short8 bv = *(const short8*)(Vb + (jo * 16 + lr) * 224 + kk * 32 + lg * 8);
        oacc[jo] = __builtin_amdgcn_mfma_f32_16x16x32_bf16(pa, bv, oacc[jo], 0, 0, 0);
      }
    }
    // write PACKED k-major
#pragma unroll
    for (int jo = 0; jo < 4; ++jo) {
      const int kc = h * 2 + (jo >> 1);
      const int lgp = (jo & 1) * 2 + (lr >> 3);
      const int e = lr & 7;
#pragma unroll
      for (int v = 0; v < 4; ++v) {
        int n = q0 + lg * 4 + v;
        if (n < 197) {
          int m = b * 197 + n;
          Apk[((size_t)(kc * 788 + (m >> 4)) * 64 + (m & 15) + 16 * lgp) * 8 + e] = f2bf(oacc[jo][v]);
        }
      }
    }
  }
}

extern "C" void kernel_launch(void* const* d_in, const int* in_sizes, int n_in,
                              void* d_out, int out_size, void* d_ws, size_t ws_size,
                              hipStream_t stream) {
  const float* x      = (const float*)d_in[0];
  const float* qkv_w  = (const float*)d_in[1];
  const float* qkv_b  = (const float*)d_in[2];
  const float* qkv_la = (const float*)d_in[3];
  const float* qkv_lb = (const float*)d_in[4];
  const float* out_w  = (const float*)d_in[5];
  const float* out_b  = (const float*)d_in[6];
  const float* out_la = (const float*)d_in[7];
  const float* out_lb = (const float*)d_in[8];
  float* out = (float*)d_out;

  const int M = 64 * 197;  // 12608 = 788*16 = 197*64
  char* p = (char*)d_ws;
  auto carve = [&](size_t bytes) {
    char* r = p;
    p += (bytes + 255) & ~(size_t)255;
    return r;
  };
  unsigned short* Apk  = (unsigned short*)carve((size_t)788 * 24 * 512 * 2);  // packed x / packed aout
  unsigned short* Wqpk = (unsigned short*)carve((size_t)144 * 24 * 512 * 2);
  unsigned short* Wopk = (unsigned short*)carve((size_t)48 * 24 * 512 * 2);
  float* lowq          = (float*)carve((size_t)M * 8 * 4);
  float* lowo          = (float*)carve((size_t)M * 8 * 4);
  unsigned short* Qg   = (unsigned short*)carve((size_t)768 * 224 * 64 * 2);
  unsigned short* Kg   = (unsigned short*)carve((size_t)768 * 224 * 64 * 2);
  unsigned short* Vtg  = (unsigned short*)carve((size_t)768 * 64 * 224 * 2);

  // merged prep: 788 (pack x + low) + 864 (pack qkv_w) + 288 (pack out_w) + 192 (V pads)
  k_prep2<<<2132, 256, 0, stream>>>(x, qkv_la, qkv_w, out_w, Apk, lowq, Wqpk, Wopk, Vtg);
  k_gp2<0, 36, 144><<<50 * 36, 256, 0, stream>>>(Apk, Wqpk, qkv_b, lowq, qkv_lb, Qg, Kg, Vtg, nullptr);
  k_attn<<<768, 256, 0, stream>>>(Qg, Kg, Vtg, Apk);  // Apk now holds packed attn-out
  k_low_pk<<<(M + 3) / 4, 256, 0, stream>>>(Apk, out_la, lowo, M);
  k_gp2<1, 12, 48><<<50 * 12, 256, 0, stream>>>(Apk, Wopk, out_b, lowo, out_lb, nullptr, nullptr, nullptr, out);
}